// Round 14
// baseline (713.796 us; speedup 1.0000x reference)
//
#include <hip/hip_runtime.h>

#define NB    256               // batch
#define NT    512               // time steps
#define NF    33                // features incl. flag channel
#define BOND  64
#define NOUT  32
#define TC    64                // chunk length
#define NCH   (NT / TC)         // 8 chunks per batch
#define MSTR  4104              // f16 stride per 64x64 slot (4096+8 -> inter-slot bank skew)

typedef _Float16 f16x4 __attribute__((ext_vector_type(4)));
typedef _Float16 f16x8 __attribute__((ext_vector_type(8)));
typedef float    f32x4 __attribute__((ext_vector_type(4)));

#define MFMA16(a, b, c) __builtin_amdgcn_mfma_f32_16x16x32_f16((a), (b), (c), 0, 0, 0)

// ---------------------------------------------------------------------------
// Phase 0: TWO packs of core channels f=1..32 into MFMA A-fragment order.
// blocks 0..255   -> cfragT: col-major flatten n = j*64+i  (verified r4-r13)
// blocks 256..511 -> cfragN: row-major flatten n = i*64+j  (verified r1)
// ---------------------------------------------------------------------------
__global__ __launch_bounds__(64) void pack_cfrag(const float* __restrict__ core,
                                                 _Float16* __restrict__ cfragT,
                                                 _Float16* __restrict__ cfragN)
{
    int bid = (int)blockIdx.x;
    bool natural = bid >= 256;
    int tid = (bid & 255) * 64 + (int)threadIdx.x;   // 0..16383
    int nt = tid >> 6, l = tid & 63;
    int g = l >> 4, c = l & 15;
    int n = nt * 16 + c;
    int i = natural ? (n >> 6) : (n & 63);
    int j = natural ? (n & 63) : (n >> 6);
    const float* src = core + (size_t)i * (NF * BOND) + (size_t)(1 + g * 8) * BOND + j;
    f16x8 v;
    #pragma unroll
    for (int m = 0; m < 8; ++m) v[m] = (_Float16)src[(size_t)m * BOND];
    _Float16* dst = natural ? cfragN : cfragT;
    *(f16x8*)(dst + (size_t)tid * 8) = v;
}

// Row-fragment read of buffer row (rblk*16 + c), k-half kh (verified pattern).
__device__ __forceinline__ f16x8 frg(const _Float16* S, int rblk, int kh,
                                     int c, int g, int sw) {
    return *(const f16x8*)(S + (rblk * 16 + c) * 64 + (((kh << 5) + (g << 3)) ^ sw));
}
// Tile writeback: Z row yr*16+c, col run xr*16+4g (verified pattern).
__device__ __forceinline__ void wrt(_Float16* S, int yr, int xr,
                                    int c, int g, int sw, f32x4 a) {
    f16x4 h;
    h[0] = (_Float16)a[0]; h[1] = (_Float16)a[1];
    h[2] = (_Float16)a[2]; h[3] = (_Float16)a[3];
    *(f16x4*)(S + (yr * 16 + c) * 64 + (((xr << 4) + (g << 2)) ^ sw)) = h;
}
__device__ __forceinline__ f16x4 diagpack(f32x4 d, int dr, float x0v) {
    f16x4 mv;
    mv[0] = (_Float16)((dr == 0) ? d[0] + x0v : d[0]);   // RNE
    mv[1] = (_Float16)((dr == 1) ? d[1] + x0v : d[1]);
    mv[2] = (_Float16)((dr == 2) ? d[2] + x0v : d[2]);
    mv[3] = (_Float16)((dr == 3) ? d[3] + x0v : d[3]);
    return mv;
}

// ---------------------------------------------------------------------------
// Phase 1: per (batch, chunk): P = prod_t M_t via dual-orientation product
// tree. Primitive (verified r6/r7): mfma(fragX, fragY) -> Z = Y·X^T, lane
// (g,c) holds Z[yr*16+c][xr*16+4g..+3]. Formation: slot t holds N(M_t) for
// even t (cfragN), T(M_t) for odd t (cfragT). Pair rule at every level
// (A_even avail N, A_odd avail T):  N-out: prim(X=T(A_odd), Y=N(A_even));
// T-out: prim(X=N(A_even), Y=T(A_odd)). Even-index -> N, odd -> T.
// Slots: L1 p:{2p,2p+1}->2p; L2 u:{4u,4u+2}->4u+1; L3 {1,5}->3,{13,9}->11;
// L4 {11,3}->7 (T(F)); apply = verified r6 chain step off slot 7.
// 6 barriers/fr vs 17.
// ---------------------------------------------------------------------------
__global__ __launch_bounds__(512, 1) void chunk_prod(const float* __restrict__ x,
                                                     const _Float16* __restrict__ cfragT,
                                                     const _Float16* __restrict__ cfragN,
                                                     _Float16* __restrict__ Pout)
{
    __shared__ __align__(16) _Float16 Mb[16 * MSTR];
    __shared__ __align__(16) _Float16 PB[2][64 * 64];
    __shared__ __align__(16) _Float16 Xl[TC][32];
    __shared__ float x0l[TC];

    const int tid = (int)threadIdx.x;
    const int l = tid & 63, w = tid >> 6;         // 8 waves
    const int g = l >> 4, c = l & 15;
    const int ch = (int)blockIdx.x, b = (int)blockIdx.y;
    const int sw = (c & 7) << 3;

    // ---- stage x chunk (verbatim) ----
    const float* xb = x + (size_t)b * (NT * NF) + (size_t)(ch * TC) * NF;
    for (int idx = tid; idx < TC * NF; idx += 512) {
        int t = idx / NF, f = idx - t * NF;
        float v = xb[idx];
        if (f == 0) x0l[t] = v;
        else        Xl[t][f - 1] = (_Float16)v;
    }
    // ---- P = I (verbatim) ----
    for (int idx = tid; idx < 4096; idx += 512) {
        int row = idx >> 6, col = idx & 63;
        PB[0][row * 64 + (col ^ ((row & 7) << 3))] = (row == col) ? (_Float16)1.f : (_Float16)0.f;
    }
    __syncthreads();

    const int rb = (w >> 1) << 4;                 // apply: wave's P row block
    const int cb = (w & 1) << 5;                  // apply: wave's P col block
    const int arow = rb + c;
    const int wcol = (cb + 4 * g) ^ sw;
    const _Float16* cfT = cfragT + ((size_t)(w * 32) * 64 + (size_t)l) * 8;
    const _Float16* cfN = cfragN + ((size_t)(w * 32) * 64 + (size_t)l) * 8;

    int pcur = 0;
    #pragma unroll 1
    for (int fr = 0; fr < 4; ++fr) {
        // ======== formation: slice t'=fr*16+c; odd c from T-pack, even from N ====
        {
            f16x8 xa  = *(const f16x8*)&Xl[fr * 16 + c][g * 8];
            float x0v = x0l[fr * 16 + c];
            #pragma unroll
            for (int q = 0; q < 32; ++q) {
                int nt = w * 32 + q;
                int rA = nt >> 2;                           // buffer row (j for T, i for N)
                int c0 = ((nt & 3) << 4) + (g << 2);        // col-run base
                int dr = rA - c0;                           // diag slot if 0..3
                _Float16* dst = &Mb[c * MSTR + (rA << 6) + (c0 ^ ((rA & 7) << 3))];
                f32x4 z = {0.f, 0.f, 0.f, 0.f};
                f16x8 caT = *(const f16x8*)(cfT + (size_t)q * 512);
                f32x4 dT = MFMA16(caT, xa, z);
                if (c & 1) *(f16x4*)dst = diagpack(dT, dr, x0v);
                f16x8 caN = *(const f16x8*)(cfN + (size_t)q * 512);
                f32x4 dN = MFMA16(caN, xa, z);
                if (!(c & 1)) *(f16x4*)dst = diagpack(dN, dr, x0v);
            }
        }
        __syncthreads();

        // ======== L1: wave p=w: slots {2p,2p+1} -> slot 2p (in-place, hoist all) ==
        {
            const _Float16* Y = Mb + (size_t)((w & 1) ? (2 * w + 1) : (2 * w)) * MSTR;
            const _Float16* X = Mb + (size_t)((w & 1) ? (2 * w) : (2 * w + 1)) * MSTR;
            _Float16* O = Mb + (size_t)(2 * w) * MSTR;
            f16x8 xf[4][2], yf[4][2];
            #pragma unroll
            for (int r = 0; r < 4; ++r) {
                xf[r][0] = frg(X, r, 0, c, g, sw); xf[r][1] = frg(X, r, 1, c, g, sw);
                yf[r][0] = frg(Y, r, 0, c, g, sw); yf[r][1] = frg(Y, r, 1, c, g, sw);
            }
            #pragma unroll
            for (int yr = 0; yr < 4; ++yr) {
                #pragma unroll
                for (int xr = 0; xr < 4; ++xr) {
                    f32x4 acc = {0.f, 0.f, 0.f, 0.f};
                    acc = MFMA16(xf[xr][0], yf[yr][0], acc);
                    acc = MFMA16(xf[xr][1], yf[yr][1], acc);
                    wrt(O, yr, xr, c, g, sw, acc);
                }
            }
        }
        __syncthreads();

        // ======== L2: u=w>>1,h=w&1: {4u(N),4u+2(T)} -> 4u+1; yr in {2h,2h+1} ======
        {
            int u = w >> 1, h = w & 1;
            const _Float16* Y = Mb + (size_t)((u & 1) ? (4 * u + 2) : (4 * u)) * MSTR;
            const _Float16* X = Mb + (size_t)((u & 1) ? (4 * u) : (4 * u + 2)) * MSTR;
            _Float16* O = Mb + (size_t)(4 * u + 1) * MSTR;
            f16x8 xf[4][2];
            #pragma unroll
            for (int r = 0; r < 4; ++r) {
                xf[r][0] = frg(X, r, 0, c, g, sw); xf[r][1] = frg(X, r, 1, c, g, sw);
            }
            #pragma unroll
            for (int yy = 0; yy < 2; ++yy) {
                int yr = 2 * h + yy;
                f16x8 y0 = frg(Y, yr, 0, c, g, sw), y1 = frg(Y, yr, 1, c, g, sw);
                #pragma unroll
                for (int xr = 0; xr < 4; ++xr) {
                    f32x4 acc = {0.f, 0.f, 0.f, 0.f};
                    acc = MFMA16(xf[xr][0], y0, acc);
                    acc = MFMA16(xf[xr][1], y1, acc);
                    wrt(O, yr, xr, c, g, sw, acc);
                }
            }
        }
        __syncthreads();

        // ======== L3: v=w>>2,h=w&3: v0:{1(N),5(T)}->3(N); v1:{9(N),13(T)}->11(T) ==
        {
            int v = w >> 2, h = w & 3;
            const _Float16* Y = Mb + (size_t)(v ? 13 : 1) * MSTR;
            const _Float16* X = Mb + (size_t)(v ? 9 : 5) * MSTR;
            _Float16* O = Mb + (size_t)(v ? 11 : 3) * MSTR;
            f16x8 xf[4][2];
            #pragma unroll
            for (int r = 0; r < 4; ++r) {
                xf[r][0] = frg(X, r, 0, c, g, sw); xf[r][1] = frg(X, r, 1, c, g, sw);
            }
            f16x8 y0 = frg(Y, h, 0, c, g, sw), y1 = frg(Y, h, 1, c, g, sw);
            #pragma unroll
            for (int xr = 0; xr < 4; ++xr) {
                f32x4 acc = {0.f, 0.f, 0.f, 0.f};
                acc = MFMA16(xf[xr][0], y0, acc);
                acc = MFMA16(xf[xr][1], y1, acc);
                wrt(O, h, xr, c, g, sw, acc);
            }
        }
        __syncthreads();

        // ======== L4: {3(N Q3_0), 11(T Q3_1)} -> 7 = T(F); yr=w>>1, xr pair ======
        {
            const _Float16* Y = Mb + (size_t)11 * MSTR;
            const _Float16* X = Mb + (size_t)3 * MSTR;
            _Float16* O = Mb + (size_t)7 * MSTR;
            int yr = w >> 1, xr0 = 2 * (w & 1);
            f16x8 y0 = frg(Y, yr, 0, c, g, sw), y1 = frg(Y, yr, 1, c, g, sw);
            #pragma unroll
            for (int xx = 0; xx < 2; ++xx) {
                int xr = xr0 + xx;
                f16x8 x0f = frg(X, xr, 0, c, g, sw), x1f = frg(X, xr, 1, c, g, sw);
                f32x4 acc = {0.f, 0.f, 0.f, 0.f};
                acc = MFMA16(x0f, y0, acc);
                acc = MFMA16(x1f, y1, acc);
                wrt(O, yr, xr, c, g, sw, acc);
            }
        }
        __syncthreads();

        // ======== apply: P <- P * F (round-6 verified chain step, Ms = slot 7) ====
        {
            const _Float16* Ms = Mb + (size_t)7 * MSTR;
            const _Float16* Ps = &PB[pcur][0];
            f16x8 a0  = *(const f16x8*)&Ps[arow * 64 + ((g * 8)      ^ sw)];
            f16x8 a1  = *(const f16x8*)&Ps[arow * 64 + ((32 + g * 8) ^ sw)];
            f16x8 b00 = frg(Ms, (cb >> 4),     0, c, g, sw);
            f16x8 b01 = frg(Ms, (cb >> 4),     1, c, g, sw);
            f16x8 b10 = frg(Ms, (cb >> 4) + 1, 0, c, g, sw);
            f16x8 b11 = frg(Ms, (cb >> 4) + 1, 1, c, g, sw);
            f32x4 acc0 = {0.f, 0.f, 0.f, 0.f}, acc1 = {0.f, 0.f, 0.f, 0.f};
            acc0 = MFMA16(b00, a0, acc0);
            acc0 = MFMA16(b01, a1, acc0);
            acc1 = MFMA16(b10, a0, acc1);
            acc1 = MFMA16(b11, a1, acc1);
            f16x4 h0, h1;                         // RNE
            h0[0] = (_Float16)acc0[0]; h0[1] = (_Float16)acc0[1];
            h0[2] = (_Float16)acc0[2]; h0[3] = (_Float16)acc0[3];
            h1[0] = (_Float16)acc1[0]; h1[1] = (_Float16)acc1[1];
            h1[2] = (_Float16)acc1[2]; h1[3] = (_Float16)acc1[3];
            if (fr == 3) {                        // chunk product -> global (f16)
                _Float16* Po = Pout + (size_t)(b * NCH + ch) * 4096;
                *(f16x4*)(Po + arow * 64 + cb + 4 * g)      = h0;
                *(f16x4*)(Po + arow * 64 + cb + 16 + 4 * g) = h1;
            } else {
                _Float16* Pn = &PB[pcur ^ 1][0];
                *(f16x4*)(Pn + arow * 64 + wcol)        = h0;
                *(f16x4*)(Pn + arow * 64 + (wcol ^ 16)) = h1;
                pcur ^= 1;
            }
        }
        __syncthreads();
    }
}

// ---------------------------------------------------------------------------
// Phase 2: per batch, v = alpha; v = v @ P_c for c=0..7; out = v @ output_core.
// P now f16 (one extra rounding per chunk boundary; f32 accumulate).
// ---------------------------------------------------------------------------
__global__ __launch_bounds__(256) void combine(const _Float16* __restrict__ P,
                                               const float* __restrict__ alpha,
                                               const float* __restrict__ oc,
                                               float* __restrict__ out)
{
    const int b = (int)blockIdx.x;
    const int tid = (int)threadIdx.x, j = tid & 63, q = tid >> 6;   // q = 0..3
    __shared__ float vb[BOND];
    __shared__ float ps[4][BOND];
    if (tid < BOND) vb[tid] = alpha[tid];
    __syncthreads();
    for (int ch = 0; ch < NCH; ++ch) {
        const _Float16* Pc = P + (size_t)(b * NCH + ch) * 4096;
        float s = 0.f;
        #pragma unroll
        for (int k = 0; k < 16; ++k) {
            int i = q * 16 + k;
            s = fmaf(vb[i], (float)Pc[i * 64 + j], s);
        }
        ps[q][j] = s;
        __syncthreads();
        if (q == 0) vb[j] = (ps[0][j] + ps[1][j]) + (ps[2][j] + ps[3][j]);
        __syncthreads();
    }
    if (tid < NOUT) {
        float s = 0.f;
        #pragma unroll 8
        for (int i = 0; i < BOND; ++i) s = fmaf(vb[i], oc[i * NOUT + tid], s);
        out[b * NOUT + tid] = s;
    }
}

extern "C" void kernel_launch(void* const* d_in, const int* in_sizes, int n_in,
                              void* d_out, int out_size, void* d_ws, size_t ws_size,
                              hipStream_t stream)
{
    const float* x     = (const float*)d_in[0];  // (256, 512, 33) f32
    const float* core  = (const float*)d_in[1];  // (64, 33, 64) f32
    const float* alpha = (const float*)d_in[2];  // (64,) f32
    const float* oc    = (const float*)d_in[3];  // (64, 32) f32
    float* out = (float*)d_out;                  // (256, 32) f32

    // workspace: [cfragT 256K][cfragN 256K][P f16: 256*8*4096*2 = 16 MB] = 17.3 MB
    _Float16* cfragT = (_Float16*)d_ws;
    _Float16* cfragN = (_Float16*)((char*)d_ws + 262144);
    _Float16* P      = (_Float16*)((char*)d_ws + 524288);

    pack_cfrag<<<dim3(512), dim3(64), 0, stream>>>(core, cfragT, cfragN);
    chunk_prod<<<dim3(NCH, NB), dim3(512), 0, stream>>>(x, cfragT, cfragN, P);
    combine<<<dim3(NB), dim3(256), 0, stream>>>(P, alpha, oc, out);
}

// Round 15
// 227.960 us; speedup vs baseline: 3.1312x; 3.1312x over previous
//
#include <hip/hip_runtime.h>

#define NB    256               // batch
#define NT    512               // time steps
#define NF    33                // features incl. flag channel
#define BOND  64
#define NOUT  32
#define TC    128               // chunk length (doubled: amortize prologue/combine)
#define NCH   (NT / TC)         // 4 chunks per batch
#define MSTR  4104              // f16 stride per staged M^T slice (4096 + 8 -> bank skew)

typedef _Float16 f16x4 __attribute__((ext_vector_type(4)));
typedef _Float16 f16x8 __attribute__((ext_vector_type(8)));
typedef float    f32x4 __attribute__((ext_vector_type(4)));

#define MFMA16(a, b, c) __builtin_amdgcn_mfma_f32_16x16x32_f16((a), (b), (c), 0, 0, 0)

// ---------------------------------------------------------------------------
// Phase 0: pack core channels f=1..32 into f16 MFMA A-fragment order,
// COLUMN-MAJOR flatten n' = j*64 + i (verbatim rounds 4-13, HW-verified).
// ---------------------------------------------------------------------------
__global__ __launch_bounds__(64) void pack_cfrag(const float* __restrict__ core,
                                                 _Float16* __restrict__ cfrag)
{
    int tid = blockIdx.x * 64 + threadIdx.x;      // 0 .. 16383
    int nt = tid >> 6, l = tid & 63;
    int g = l >> 4, c = l & 15;
    int n = nt * 16 + c;
    int i = n & 63, j = n >> 6;                   // column-major flatten
    const float* src = core + (size_t)i * (NF * BOND) + (size_t)(1 + g * 8) * BOND + j;
    f16x8 v;
    #pragma unroll
    for (int m = 0; m < 8; ++m) v[m] = (_Float16)src[(size_t)m * BOND];
    *(f16x8*)(cfrag + (size_t)tid * 8) = v;
}

// ---------------------------------------------------------------------------
// Phase 1: ROUND-13 VERBATIM structure (round-6 formation: creg + full unroll;
// chain: B-prefetch + swapped-slot MFMA + vector P' writes). ONLY change:
// TC 64 -> 128 (fr loop 8x instead of 4x) — halves block count (prologue
// amortization) and combine work. Hot-loop code byte-identical.
// ---------------------------------------------------------------------------
__global__ __launch_bounds__(512, 1) void chunk_prod(const float* __restrict__ x,
                                                     const _Float16* __restrict__ cfrag,
                                                     float* __restrict__ Pout)
{
    __shared__ __align__(16) _Float16 PB[2][64 * 64];
    __shared__ __align__(16) _Float16 Mb[16 * MSTR];
    __shared__ __align__(16) _Float16 Xl[TC][32];
    __shared__ float x0l[TC];

    const int tid = (int)threadIdx.x;
    const int l = tid & 63, w = tid >> 6;         // 8 waves
    const int g = l >> 4, c = l & 15;
    const int ch = (int)blockIdx.x, b = (int)blockIdx.y;

    // ---- stage x chunk ----
    const float* xb = x + (size_t)b * (NT * NF) + (size_t)(ch * TC) * NF;
    for (int idx = tid; idx < TC * NF; idx += 512) {
        int t = idx / NF, f = idx - t * NF;
        float v = xb[idx];
        if (f == 0) x0l[t] = v;
        else        Xl[t][f - 1] = (_Float16)v;
    }
    // ---- P = I (row-major, swizzled) ----
    for (int idx = tid; idx < 4096; idx += 512) {
        int row = idx >> 6, col = idx & 63;
        PB[0][row * 64 + (col ^ ((row & 7) << 3))] = (row == col) ? (_Float16)1.f : (_Float16)0.f;
    }

    // ---- cache this wave's 32 cfrag tiles in registers (round-6 verbatim) ----
    f16x8 creg[32];
    {
        const _Float16* cf = cfrag + (size_t)w * 16384 + (size_t)l * 8;
        #pragma unroll
        for (int q = 0; q < 32; ++q) creg[q] = *(const f16x8*)(cf + (size_t)q * 512);
    }
    __syncthreads();

    const int sw = (c & 7) << 3;                  // row-XOR for all chain reads
    const int rb = (w >> 1) << 4;                 // wave's P row block: 0/16/32/48
    const int cb = (w & 1) << 5;                  // wave's P col block: 0/32
    const int arow = rb + c;
    const int wcol = (cb + 4 * g) ^ sw;           // P' write col base (row = arow)
    const int bo0 = (cb + c) * 64      + ((g * 8)      ^ sw);
    const int bo1 = (cb + c) * 64      + ((32 + g * 8) ^ sw);
    const int bo2 = (cb + 16 + c) * 64 + ((g * 8)      ^ sw);
    const int bo3 = (cb + 16 + c) * 64 + ((32 + g * 8) ^ sw);

    int pcur = 0;
    #pragma unroll 1
    for (int fr = 0; fr < TC / 16; ++fr) {        // 8 groups of 16 steps
        // ======== formation: M^T slices for t' = fr*16 + c (round-6 verbatim) ====
        f16x8 xa  = *(const f16x8*)&Xl[fr * 16 + c][g * 8];
        float x0v = x0l[fr * 16 + c];
        #pragma unroll
        for (int q = 0; q < 32; ++q) {
            int nt = w * 32 + q;
            f32x4 zero = {0.f, 0.f, 0.f, 0.f};
            f32x4 d = MFMA16(creg[q], xa, zero);
            // lane holds M[i0..i0+3][j], i0 = (nt&3)*16 + g*4, j = nt>>2
            int j  = nt >> 2;
            int i0 = ((nt & 3) << 4) + (g << 2);
            int dr = j - i0;                      // diag slot if 0..3 (compile-time per q)
            f16x4 mv;
            mv[0] = (_Float16)((dr == 0) ? d[0] + x0v : d[0]);   // RNE
            mv[1] = (_Float16)((dr == 1) ? d[1] + x0v : d[1]);
            mv[2] = (_Float16)((dr == 2) ? d[2] + x0v : d[2]);
            mv[3] = (_Float16)((dr == 3) ? d[3] + x0v : d[3]);
            *(f16x4*)(&Mb[c * MSTR + (j << 6) + (i0 ^ ((j & 7) << 3))]) = mv;
        }
        __syncthreads();

        // ======== chain 16 steps: B-prefetch, swapped-slot MFMA ========
        f16x8 pf[2][4];                           // static parity-indexed sets
        pf[0][0] = *(const f16x8*)(Mb + bo0);     // B(0), post-formation-barrier
        pf[0][1] = *(const f16x8*)(Mb + bo1);
        pf[0][2] = *(const f16x8*)(Mb + bo2);
        pf[0][3] = *(const f16x8*)(Mb + bo3);
        #pragma unroll 4
        for (int s = 0; s < 16; ++s) {
            const int cu = s & 1, nx = cu ^ 1;    // compile-time per unrolled body
            const _Float16* Ps = &PB[pcur][0];
            f16x8 a0 = *(const f16x8*)&Ps[arow * 64 + ((g * 8)      ^ sw)];
            f16x8 a1 = *(const f16x8*)&Ps[arow * 64 + ((32 + g * 8) ^ sw)];
            if (s < 15) {                         // prefetch B(s+1): Mb immutable this fr
                const _Float16* Mn = Mb + (s + 1) * MSTR;
                pf[nx][0] = *(const f16x8*)(Mn + bo0);
                pf[nx][1] = *(const f16x8*)(Mn + bo1);
                pf[nx][2] = *(const f16x8*)(Mn + bo2);
                pf[nx][3] = *(const f16x8*)(Mn + bo3);
            }
            f32x4 acc0 = {0.f, 0.f, 0.f, 0.f}, acc1 = {0.f, 0.f, 0.f, 0.f};
            // swapped slots (round-6 verified): lane holds P'[arow][cb(+16)+4g..+3]
            acc0 = MFMA16(pf[cu][0], a0, acc0);
            acc0 = MFMA16(pf[cu][1], a1, acc0);
            acc1 = MFMA16(pf[cu][2], a0, acc1);
            acc1 = MFMA16(pf[cu][3], a1, acc1);

            if (fr == (TC / 16 - 1) && s == 15) { // final chunk product in f32
                float* Po = Pout + (size_t)(b * NCH + ch) * 4096;
                *(f32x4*)(Po + arow * 64 + cb + 4 * g)      = acc0;
                *(f32x4*)(Po + arow * 64 + cb + 16 + 4 * g) = acc1;
            } else {
                _Float16* Pn = &PB[pcur ^ 1][0];
                f16x4 h0, h1;                     // RNE, as round 6
                h0[0] = (_Float16)acc0[0]; h0[1] = (_Float16)acc0[1];
                h0[2] = (_Float16)acc0[2]; h0[3] = (_Float16)acc0[3];
                h1[0] = (_Float16)acc1[0]; h1[1] = (_Float16)acc1[1];
                h1[2] = (_Float16)acc1[2]; h1[3] = (_Float16)acc1[3];
                *(f16x4*)(Pn + arow * 64 + wcol)        = h0;
                *(f16x4*)(Pn + arow * 64 + (wcol ^ 16)) = h1;
            }
            __syncthreads();
            pcur ^= 1;
        }
    }
}

// ---------------------------------------------------------------------------
// Phase 2: per batch, v = alpha; v = v @ P_c for c=0..3; out = v @ output_core.
// ---------------------------------------------------------------------------
__global__ __launch_bounds__(256) void combine(const float* __restrict__ P,
                                               const float* __restrict__ alpha,
                                               const float* __restrict__ oc,
                                               float* __restrict__ out)
{
    const int b = (int)blockIdx.x;
    const int tid = (int)threadIdx.x, j = tid & 63, q = tid >> 6;   // q = 0..3
    __shared__ float vb[BOND];
    __shared__ float ps[4][BOND];
    if (tid < BOND) vb[tid] = alpha[tid];
    __syncthreads();
    for (int ch = 0; ch < NCH; ++ch) {
        const float* Pc = P + (size_t)(b * NCH + ch) * 4096;
        float s = 0.f;
        #pragma unroll
        for (int k = 0; k < 16; ++k) {
            int i = q * 16 + k;
            s = fmaf(vb[i], Pc[i * 64 + j], s);
        }
        ps[q][j] = s;
        __syncthreads();
        if (q == 0) vb[j] = (ps[0][j] + ps[1][j]) + (ps[2][j] + ps[3][j]);
        __syncthreads();
    }
    if (tid < NOUT) {
        float s = 0.f;
        #pragma unroll 8
        for (int i = 0; i < BOND; ++i) s = fmaf(vb[i], oc[i * NOUT + tid], s);
        out[b * NOUT + tid] = s;
    }
}

extern "C" void kernel_launch(void* const* d_in, const int* in_sizes, int n_in,
                              void* d_out, int out_size, void* d_ws, size_t ws_size,
                              hipStream_t stream)
{
    const float* x     = (const float*)d_in[0];  // (256, 512, 33) f32
    const float* core  = (const float*)d_in[1];  // (64, 33, 64) f32
    const float* alpha = (const float*)d_in[2];  // (64,) f32
    const float* oc    = (const float*)d_in[3];  // (64, 32) f32
    float* out = (float*)d_out;                  // (256, 32) f32

    // workspace: [cfrag f16: 262144 B][P f32: 256*4*4096*4 = 16777216 B]
    _Float16* cfrag = (_Float16*)d_ws;
    float*    P     = (float*)((char*)d_ws + 262144);

    pack_cfrag<<<dim3(256), dim3(64), 0, stream>>>(core, cfrag);
    chunk_prod<<<dim3(NCH, NB), dim3(512), 0, stream>>>(x, cfrag, P);
    combine<<<dim3(NB), dim3(256), 0, stream>>>(P, alpha, oc, out);
}